// Round 9
// baseline (163.284 us; speedup 1.0000x reference)
//
#include <hip/hip_runtime.h>
#include <hip/hip_bf16.h>
#include <math.h>

using bf16x8 = __attribute__((ext_vector_type(8))) __bf16;
using f32x16 = __attribute__((ext_vector_type(16))) float;

#define B_SZ    8192
#define S_STEPS 51
#define M_ROWS  (B_SZ * S_STEPS)
#define TROWS   64            // rows per block tile

__device__ __forceinline__ f32x16 mfma32(bf16x8 a, bf16x8 b, f32x16 c) {
    return __builtin_amdgcn_mfma_f32_32x32x16_bf16(a, b, c, 0, 0, 0);
}

// ---------------- quadrature constants (fp64, matches numpy) ----------------
__global__ void ccq_kernel(float* __restrict__ ccw, float* __restrict__ stp) {
    int s = threadIdx.x;
    if (s >= S_STEPS) return;
    double pi50 = M_PI / 50.0;
    double acc = 0.0;
    for (int j = 0; j <= 50; j += 2) {           // odd j have weight 0
        double wq = (j == 0) ? 1.0 : 2.0 / (1.0 - (double)(j * j));
        double m;
        if (s == 0) m = 0.5;
        else if (s == 50) m = 0.5;               // 0.5*cos(j*pi), j even -> 0.5
        else m = cos((double)(j * s) * pi50);
        acc += m * wq;
    }
    ccw[s] = (float)(acc * (2.0 / 50.0));
    stp[s] = (float)cos((double)s * pi50);
}

// ---- pack fp32 weights (Ksrc x Nsrc row-major) into 32x32x16 B-frag order --
// dst[((cg*KST+ks)*64 + lane)*8 + j] = W[kk][col]
//   col = cg*32 + (lane&31), k-position p = ks*16 + (lane>>5)*8 + j
//   kk = p, or chi(p) when the layer's input comes from the paired epilogue:
//   chi: within each 64-block, stored elem e holds feature (e>>1) + 32*(e&1)
struct PackArgs {
    const float* src[8];
    __hip_bfloat16* dst[8];
    int Ks[8], Ns[8], KST[8], perm[8];
    int prefix[9];   // element-count prefix sums
};

__global__ void pack_all(PackArgs pa) {
    int idx = blockIdx.x * 256 + threadIdx.x;
    if (idx >= pa.prefix[8]) return;
    int m = 0;
    while (idx >= pa.prefix[m + 1]) ++m;
    int e = idx - pa.prefix[m];
    int KST = pa.KST[m];
    int j    = e & 7;
    int lane = (e >> 3) & 63;
    int ks   = (e >> 9) % KST;
    int cg   = (e >> 9) / KST;
    int col = cg * 32 + (lane & 31);
    int k   = ks * 16 + (lane >> 5) * 8 + j;
    int kk  = pa.perm[m] ? ((k & ~63) | (((k & 63) >> 1) + 32 * (k & 1))) : k;
    float v = (kk < pa.Ks[m] && col < pa.Ns[m]) ? pa.src[m][kk * pa.Ns[m] + col] : 0.0f;
    ((__bf16*)pa.dst[m])[e] = (__bf16)v;
}

// ---------------- fused MLP building blocks ----------------
// act LDS: 64 rows x 256 feats bf16, 16B chunks XOR-swizzled with FULL 5-bit
// row key: idx16(row, chunk) = row*32 + (chunk ^ (row & 31)).
// R8 lesson: MASK=7 with CHUNKS=32 left slots repeating every 8 rows -> the
// A-frag ds_read_b128 (32 lanes, 32 distinct rows, same chunk) hit 4 lanes
// per 16B slot = 4-way conflict (8.8M conflict cycles). With &31 the slot
// map is bijective across 32 rows -> 32 distinct slots -> conflict-free.
// 4 waves (256 thr); each wave = ALL 64 rows x 64 cols (cols wc*64..+63).
// 32x32x16 frags: acc f32x16[2][2] (64 regs). A-red 4, B-red 1 (optimal).
// Register plan: ~124 total <= 128 => 4 blocks/CU (launch_bounds(256,4)).

template<int KST, int CHUNKS, int MASK>
__device__ __forceinline__ void gemm_compute(const __bf16* __restrict__ actIn,
                                             const __bf16* __restrict__ wpack,
                                             f32x16 (&acc)[2][2],
                                             int wc, int lane) {
    const bf16x8* wp = (const bf16x8*)wpack;
    const int la = lane & 31, hi = lane >> 5;
#pragma unroll 4
    for (int ks = 0; ks < KST; ++ks) {
        bf16x8 b0 = wp[((wc * 2 + 0) * KST + ks) * 64 + lane];
        bf16x8 b1 = wp[((wc * 2 + 1) * KST + ks) * 64 + lane];
        int chunk = ks * 2 + hi;
#pragma unroll
        for (int m = 0; m < 2; ++m) {
            int row = m * 32 + la;
            bf16x8 af = *(const bf16x8*)(actIn + (row * CHUNKS + (chunk ^ (row & MASK))) * 8);
            acc[m][0] = mfma32(af, b0, acc[m][0]);
            acc[m][1] = mfma32(af, b1, acc[m][1]);
        }
    }
}

// epilogue: bias+relu; pack feature pair (F, F+32) -> one dword LDS write.
// Stored chi-permuted; consumed by chi-packed weights next layer.
// Bank check (&31 swizzle): lanes 0-31 share a row, 32 distinct dwords of a
// permuted chunk set -> 32 banks; hi-half is a different row -> 2-way = free.
__device__ __forceinline__ void epilogue_store(f32x16 (&acc)[2][2],
                                               const float* __restrict__ bias,
                                               __bf16* __restrict__ actOut,
                                               int wc, int lane) {
    const int la = lane & 31, hi = lane >> 5;
    unsigned* dst = (unsigned*)actOut;
    int F = wc * 64 + la;
    float b0 = bias[F], b1 = bias[F + 32];
    int d = wc * 32 + la;          // dword index within row (128/row)
    int c = d >> 2, w = d & 3;
#pragma unroll
    for (int m = 0; m < 2; ++m) {
#pragma unroll
        for (int r = 0; r < 16; ++r) {
            int row = m * 32 + (r & 3) + 8 * (r >> 2) + 4 * hi;
            float v0 = fmaxf(acc[m][0][r] + b0, 0.0f);
            float v1 = fmaxf(acc[m][1][r] + b1, 0.0f);
            union { __bf16 h2[2]; unsigned u; } cv;
            cv.h2[0] = (__bf16)v0; cv.h2[1] = (__bf16)v1;
            dst[(row * 32 + (c ^ (row & 31))) * 4 + w] = cv.u;
        }
    }
}

// final layer: K=256 (16 ksteps of 16), N padded to 32; waves 0,1 x 32 rows.
// Reads chi-ordered activations (&31 swizzle); wpack chi-packed.
template<int MODE>
__device__ __forceinline__ void final_layer(const __bf16* __restrict__ actIn,
                                            const __bf16* __restrict__ wpack,
                                            const float* __restrict__ bias,
                                            float* __restrict__ out0,
                                            float* __restrict__ out1,
                                            int rb, int wid, int lane) {
    const bf16x8* wp = (const bf16x8*)wpack;
    const int la = lane & 31, hi = lane >> 5;
    f32x16 acc = (f32x16)0.0f;
    int row = wid * 32 + la;
#pragma unroll 4
    for (int ks = 0; ks < 16; ++ks) {
        int chunk = ks * 2 + hi;
        bf16x8 af = *(const bf16x8*)(actIn + (row * 32 + (chunk ^ (row & 31))) * 8);
        acc = mfma32(af, wp[ks * 64 + lane], acc);
    }
    if (MODE == 0) {
        if (la == 0) {
            float b = bias[0];
#pragma unroll
            for (int r = 0; r < 16; ++r) {
                int rr = wid * 32 + (r & 3) + 8 * (r >> 2) + 4 * hi;
                float v = acc[r] + b;
                out0[rb + rr] = (v > 0.0f) ? (v + 1.0f) : expf(v);  // elu+1
            }
        }
    } else {
        if (la < 2) {
            float b = bias[la];
            float* dst = (la == 0) ? out0 : out1;
#pragma unroll
            for (int r = 0; r < 16; ++r) {
                int rr = wid * 32 + (r & 3) + 8 * (r >> 2) + 4 * hi;
                dst[rb + rr] = acc[r] + b;
            }
        }
    }
}

// MODE 0: integrand net, rows = s*8192 + i, input [x*(step+1)/2, h(7)], out dz
// MODE 1: h-net, rows = i, input [h(7)], out (offset, log-scale)
template<int MODE>
__global__ __launch_bounds__(256, 4) void mlp_kernel(
    const float* __restrict__ x, const float* __restrict__ h,
    const float* __restrict__ steps,
    const __bf16* __restrict__ w0p, const __bf16* __restrict__ w1p,
    const __bf16* __restrict__ w2p, const __bf16* __restrict__ w3p,
    const float* __restrict__ b0, const float* __restrict__ b1,
    const float* __restrict__ b2, const float* __restrict__ b3,
    float* __restrict__ out0, float* __restrict__ out1) {
    __shared__ __bf16 act[TROWS * 256];   // 32 KB, single in-place buffer
    __shared__ __bf16 zin[TROWS * 32];    // 4 KB input tile

    int tid  = threadIdx.x;
    int lane = tid & 63;
    int wid  = tid >> 6;   // 0..3
    int wc   = wid;
    int rb   = blockIdx.x * TROWS;

    // build padded input tile (64 rows x 32 cols, swizzled CHUNKS=4/MASK=3)
    {
        int row   = tid >> 2;          // 0..63
        int cpart = tid & 3;
        float vals[8];
        if (MODE == 0) {
            int s  = rb >> 13;
            int i  = (rb & (B_SZ - 1)) + row;
            float sc = (steps[s] + 1.0f) * 0.5f;
#pragma unroll
            for (int j = 0; j < 8; ++j) {
                int c = cpart * 8 + j;
                float v = 0.0f;
                if (c == 0) v = x[i] * sc;
                else if (c < 8) v = h[i * 7 + c - 1];
                vals[j] = v;
            }
        } else {
            int i = rb + row;
#pragma unroll
            for (int j = 0; j < 8; ++j) {
                int c = cpart * 8 + j;
                vals[j] = (c < 7) ? h[i * 7 + c] : 0.0f;
            }
        }
        bf16x8 zv;
#pragma unroll
        for (int j = 0; j < 8; ++j) zv[j] = (__bf16)vals[j];
        int zidx = (row * 4 + (cpart ^ (row & 3))) * 8;
        *(bf16x8*)(zin + zidx) = zv;
    }
    __syncthreads();

    f32x16 acc[2][2];

    // L0: 32(pad) -> 256, reads zin, writes act (distinct buffers)
#pragma unroll
    for (int m = 0; m < 2; ++m)
#pragma unroll
        for (int n = 0; n < 2; ++n) acc[m][n] = (f32x16)0.0f;
    gemm_compute<2, 4, 3>(zin, w0p, acc, wc, lane);
    epilogue_store(acc, b0, act, wc, lane);
    __syncthreads();

    // L1: 256 -> 256, in-place: compute, barrier, store, barrier
#pragma unroll
    for (int m = 0; m < 2; ++m)
#pragma unroll
        for (int n = 0; n < 2; ++n) acc[m][n] = (f32x16)0.0f;
    gemm_compute<16, 32, 31>(act, w1p, acc, wc, lane);
    __syncthreads();
    epilogue_store(acc, b1, act, wc, lane);
    __syncthreads();

    // L2: 256 -> 256, in-place
#pragma unroll
    for (int m = 0; m < 2; ++m)
#pragma unroll
        for (int n = 0; n < 2; ++n) acc[m][n] = (f32x16)0.0f;
    gemm_compute<16, 32, 31>(act, w2p, acc, wc, lane);
    __syncthreads();
    epilogue_store(acc, b2, act, wc, lane);
    __syncthreads();

    // final layer: waves 0,1 cover the 64 rows
    if (wid < 2)
        final_layer<MODE>(act, w3p, b3, out0, out1, rb, wid, lane);
}

// ---------------- final reduction ----------------
__global__ void reduce_kernel(const float* __restrict__ dz, const float* __restrict__ x,
                              const float* __restrict__ ho, const float* __restrict__ hs,
                              const float* __restrict__ ccw, float* __restrict__ out) {
    __shared__ float w[S_STEPS];
    int t = threadIdx.x;
    if (t < S_STEPS) w[t] = ccw[t];
    __syncthreads();
    int i = blockIdx.x * blockDim.x + t;
    float acc = 0.0f;
    for (int s = 0; s < S_STEPS; ++s) acc += dz[s * B_SZ + i] * w[s];
    float integral = acc * x[i] * 0.5f;
    out[i] = expf(hs[i]) * integral + ho[i];
}

extern "C" void kernel_launch(void* const* d_in, const int* in_sizes, int n_in,
                              void* d_out, int out_size, void* d_ws, size_t ws_size,
                              hipStream_t stream) {
    (void)in_sizes; (void)n_in; (void)out_size; (void)ws_size;
    const float* x = (const float*)d_in[0];
    const float* h = (const float*)d_in[1];
    const float* iW[4] = {(const float*)d_in[2], (const float*)d_in[4],
                          (const float*)d_in[6], (const float*)d_in[8]};
    const float* ib[4] = {(const float*)d_in[3], (const float*)d_in[5],
                          (const float*)d_in[7], (const float*)d_in[9]};
    const float* hW[4] = {(const float*)d_in[10], (const float*)d_in[12],
                          (const float*)d_in[14], (const float*)d_in[16]};
    const float* hb[4] = {(const float*)d_in[11], (const float*)d_in[13],
                          (const float*)d_in[15], (const float*)d_in[17]};

    size_t off = 0;
    auto alloc = [&](size_t bytes) -> void* {
        void* p = (char*)d_ws + off;
        off += (bytes + 255) & ~(size_t)255;
        return p;
    };
    float*  dz   = (float*)alloc((size_t)M_ROWS * 4);
    float*  ho   = (float*)alloc(B_SZ * 4);
    float*  hs   = (float*)alloc(B_SZ * 4);
    float*  ccw  = (float*)alloc(64 * 4);
    float*  stp  = (float*)alloc(64 * 4);
    __bf16* iW0p = (__bf16*)alloc(8 * 2 * 512 * 2);
    __bf16* iW1p = (__bf16*)alloc(8 * 16 * 512 * 2);
    __bf16* iW2p = (__bf16*)alloc(8 * 16 * 512 * 2);
    __bf16* iW3p = (__bf16*)alloc(1 * 16 * 512 * 2);
    __bf16* hW0p = (__bf16*)alloc(8 * 2 * 512 * 2);
    __bf16* hW1p = (__bf16*)alloc(8 * 16 * 512 * 2);
    __bf16* hW2p = (__bf16*)alloc(8 * 16 * 512 * 2);
    __bf16* hW3p = (__bf16*)alloc(1 * 16 * 512 * 2);

    ccq_kernel<<<1, 64, 0, stream>>>(ccw, stp);

    PackArgs pa;
    const float* srcs[8] = {iW[0], iW[1], iW[2], iW[3], hW[0], hW[1], hW[2], hW[3]};
    __bf16*      dsts[8] = {iW0p, iW1p, iW2p, iW3p, hW0p, hW1p, hW2p, hW3p};
    int Ks[8]  = {8, 256, 256, 256, 7, 256, 256, 256};
    int Ns[8]  = {256, 256, 256, 1, 256, 256, 256, 2};
    int KST[8] = {2, 16, 16, 16, 2, 16, 16, 16};
    int CG[8]  = {8, 8, 8, 1, 8, 8, 8, 1};
    int PM[8]  = {0, 1, 1, 1, 0, 1, 1, 1};   // chi on layers fed by paired epilogue
    int pfx = 0;
    for (int m = 0; m < 8; ++m) {
        pa.src[m] = srcs[m];
        pa.dst[m] = (__hip_bfloat16*)dsts[m];
        pa.Ks[m] = Ks[m]; pa.Ns[m] = Ns[m]; pa.KST[m] = KST[m]; pa.perm[m] = PM[m];
        pa.prefix[m] = pfx;
        pfx += CG[m] * KST[m] * 512;
    }
    pa.prefix[8] = pfx;
    pack_all<<<(pfx + 255) / 256, 256, 0, stream>>>(pa);

    mlp_kernel<0><<<M_ROWS / TROWS, 256, 0, stream>>>(
        x, h, stp, iW0p, iW1p, iW2p, iW3p, ib[0], ib[1], ib[2], ib[3], dz, dz);
    mlp_kernel<1><<<B_SZ / TROWS, 256, 0, stream>>>(
        x, h, stp, hW0p, hW1p, hW2p, hW3p, hb[0], hb[1], hb[2], hb[3], ho, hs);

    reduce_kernel<<<B_SZ / 256, 256, 0, stream>>>(dz, x, ho, hs, ccw, (float*)d_out);
}

// Round 10
// 157.613 us; speedup vs baseline: 1.0360x; 1.0360x over previous
//
#include <hip/hip_runtime.h>
#include <hip/hip_bf16.h>
#include <math.h>

using bf16x8 = __attribute__((ext_vector_type(8))) __bf16;
using f32x16 = __attribute__((ext_vector_type(16))) float;

#define B_SZ    8192
#define S_STEPS 51
#define M_ROWS  (B_SZ * S_STEPS)
#define TROWS   64            // rows per block tile

__device__ __forceinline__ f32x16 mfma32(bf16x8 a, bf16x8 b, f32x16 c) {
    return __builtin_amdgcn_mfma_f32_32x32x16_bf16(a, b, c, 0, 0, 0);
}

// ---------------- quadrature constants (fp64, matches numpy) ----------------
__global__ void ccq_kernel(float* __restrict__ ccw, float* __restrict__ stp) {
    int s = threadIdx.x;
    if (s >= S_STEPS) return;
    double pi50 = M_PI / 50.0;
    double acc = 0.0;
    for (int j = 0; j <= 50; j += 2) {           // odd j have weight 0
        double wq = (j == 0) ? 1.0 : 2.0 / (1.0 - (double)(j * j));
        double m;
        if (s == 0) m = 0.5;
        else if (s == 50) m = 0.5;               // 0.5*cos(j*pi), j even -> 0.5
        else m = cos((double)(j * s) * pi50);
        acc += m * wq;
    }
    ccw[s] = (float)(acc * (2.0 / 50.0));
    stp[s] = (float)cos((double)s * pi50);
}

// ---- pack fp32 weights (Ksrc x Nsrc row-major) into 32x32x16 B-frag order --
// dst[((cg*KST+ks)*64 + lane)*8 + j] = W[kk][col]
//   col = cg*32 + (lane&31), k-position p = ks*16 + (lane>>5)*8 + j
//   kk = p, or chi(p) when the layer's input comes from the paired epilogue:
//   chi: within each 64-block, stored elem e holds feature (e>>1) + 32*(e&1)
struct PackArgs {
    const float* src[8];
    __hip_bfloat16* dst[8];
    int Ks[8], Ns[8], KST[8], perm[8];
    int prefix[9];   // element-count prefix sums
};

__global__ void pack_all(PackArgs pa) {
    int idx = blockIdx.x * 256 + threadIdx.x;
    if (idx >= pa.prefix[8]) return;
    int m = 0;
    while (idx >= pa.prefix[m + 1]) ++m;
    int e = idx - pa.prefix[m];
    int KST = pa.KST[m];
    int j    = e & 7;
    int lane = (e >> 3) & 63;
    int ks   = (e >> 9) % KST;
    int cg   = (e >> 9) / KST;
    int col = cg * 32 + (lane & 31);
    int k   = ks * 16 + (lane >> 5) * 8 + j;
    int kk  = pa.perm[m] ? ((k & ~63) | (((k & 63) >> 1) + 32 * (k & 1))) : k;
    float v = (kk < pa.Ks[m] && col < pa.Ns[m]) ? pa.src[m][kk * pa.Ns[m] + col] : 0.0f;
    ((__bf16*)pa.dst[m])[e] = (__bf16)v;
}

// ---------------- fused MLP building blocks ----------------
// act LDS: 64 rows x 256 feats bf16, 16B chunks XOR-swizzled (bijective &31):
//   byte(row, chunk) = row*512 + ((chunk ^ (row&31))<<4), chunk = ks*2+hi.
// Strength-reduced: (a^b)<<4 = (a<<4)^(b<<4) and chunk = (ks<<1)|hi, so
//   byte = C + ((ks<<5) ^ D), C = row*512 + ((hi^(row&1))<<4), D = (row&30)<<4.
// 4 waves (256 thr); each wave = ALL 64 rows x 64 cols. A-red 4, B-red 1.
// acc f32x16[2][2] (64 regs); total ~124/wave -> 4 blocks/CU.
// s_setprio(1) over the compute loop: blocks on a CU are phase-diverse
// (compute vs epilogue) -> T5's favorable regime, not lockstep-GEMM.

template<int KST>
__device__ __forceinline__ void gemm_compute(const __bf16* __restrict__ actIn,
                                             const __bf16* __restrict__ wpack,
                                             f32x16 (&acc)[2][2],
                                             int wc, int lane) {
    const bf16x8* wp = (const bf16x8*)wpack;
    const int la = lane & 31, hi = lane >> 5;
    const char* base = (const char*)actIn;
    const int C0 = la * 512 + ((hi ^ (la & 1)) << 4);   // m=0 row = la
    const int D  = (la & 30) << 4;                       // same for both m
    __builtin_amdgcn_s_setprio(1);
#pragma unroll
    for (int ks = 0; ks < KST; ++ks) {
        bf16x8 b0 = wp[((wc * 2 + 0) * KST + ks) * 64 + lane];
        bf16x8 b1 = wp[((wc * 2 + 1) * KST + ks) * 64 + lane];
        const int kv = ks << 5;
        bf16x8 a0 = *(const bf16x8*)(base + C0 + (kv ^ D));
        bf16x8 a1 = *(const bf16x8*)(base + C0 + 16384 + (kv ^ D));
        acc[0][0] = mfma32(a0, b0, acc[0][0]);
        acc[0][1] = mfma32(a0, b1, acc[0][1]);
        acc[1][0] = mfma32(a1, b0, acc[1][0]);
        acc[1][1] = mfma32(a1, b1, acc[1][1]);
    }
    __builtin_amdgcn_s_setprio(0);
}

// L0 direct from global: input z = [x*sc, h0..h6] (MODE0) / [h0..h6] (MODE1),
// zero-padded to K=16. A-layout: lane holds row = m*32+(lane&31),
// k = hi*8+j -> hi=0 lanes carry the 8 real features, hi=1 lanes are zero.
template<int MODE>
__device__ __forceinline__ void l0_compute(const float* __restrict__ x,
                                           const float* __restrict__ h,
                                           float sc,
                                           const __bf16* __restrict__ w0p,
                                           f32x16 (&acc)[2][2],
                                           int rb, int wc, int lane) {
    const bf16x8* wp = (const bf16x8*)w0p;
    const int la = lane & 31, hi = lane >> 5;
    bf16x8 a[2];
#pragma unroll
    for (int m = 0; m < 2; ++m) {
        bf16x8 v = (bf16x8)(__bf16)0.0f;
        if (hi == 0) {
            int row = m * 32 + la;
            int i = (MODE == 0) ? ((rb & (B_SZ - 1)) + row) : (rb + row);
            const float* hp = h + i * 7;
            if (MODE == 0) {
                v[0] = (__bf16)(x[i] * sc);
#pragma unroll
                for (int j = 0; j < 7; ++j) v[j + 1] = (__bf16)hp[j];
            } else {
#pragma unroll
                for (int j = 0; j < 7; ++j) v[j] = (__bf16)hp[j];
            }
        }
        a[m] = v;
    }
    bf16x8 b0 = wp[(wc * 2 + 0) * 64 + lane];
    bf16x8 b1 = wp[(wc * 2 + 1) * 64 + lane];
    acc[0][0] = mfma32(a[0], b0, acc[0][0]);
    acc[0][1] = mfma32(a[0], b1, acc[0][1]);
    acc[1][0] = mfma32(a[1], b0, acc[1][0]);
    acc[1][1] = mfma32(a[1], b1, acc[1][1]);
}

// epilogue: bias+relu; pack feature pair (F, F+32) -> one dword LDS write.
// Stored chi-permuted; consumed by chi-packed weights next layer.
// Strength-reduced store addr (see derivation in R10 notes):
//   row = m*32 + 4*hi + K_r, K_r = (r&3)+8*(r>>2) (bit2 free),
//   byte = P + m*16384 + K_r*512 + (cH4 ^ (K_r<<4)),
//   P = hi*2048 + (w<<2), cH4 = (c ^ (hi<<2))<<4, d = wc*32+la, c=d>>2, w=d&3.
__device__ __forceinline__ void epilogue_store(f32x16 (&acc)[2][2],
                                               const float* __restrict__ bias,
                                               __bf16* __restrict__ actOut,
                                               int wc, int lane) {
    const int la = lane & 31, hi = lane >> 5;
    char* dst = (char*)actOut;
    int F = wc * 64 + la;
    float b0v = bias[F], b1v = bias[F + 32];
    int d = wc * 32 + la;
    const int cH4 = ((d >> 2) ^ (hi << 2)) << 4;
    const int P   = hi * 2048 + ((d & 3) << 2);
#pragma unroll
    for (int m = 0; m < 2; ++m) {
#pragma unroll
        for (int r = 0; r < 16; ++r) {
            const int K_r = (r & 3) + 8 * (r >> 2);
            float v0 = fmaxf(acc[m][0][r] + b0v, 0.0f);
            float v1 = fmaxf(acc[m][1][r] + b1v, 0.0f);
            union { __bf16 h2[2]; unsigned u; } cv;
            cv.h2[0] = (__bf16)v0; cv.h2[1] = (__bf16)v1;
            *(unsigned*)(dst + P + m * 16384 + K_r * 512 + (cH4 ^ (K_r << 4))) = cv.u;
        }
    }
}

// final layer: K=256 (16 ksteps), N padded to 32; waves 0,1 x 32 rows.
// Reads chi-ordered activations; wpack chi-packed.
template<int MODE>
__device__ __forceinline__ void final_layer(const __bf16* __restrict__ actIn,
                                            const __bf16* __restrict__ wpack,
                                            const float* __restrict__ bias,
                                            float* __restrict__ out0,
                                            float* __restrict__ out1,
                                            int rb, int wid, int lane) {
    const bf16x8* wp = (const bf16x8*)wpack;
    const int la = lane & 31, hi = lane >> 5;
    const char* base = (const char*)actIn;
    const int C = (wid * 32 + la) * 512 + ((hi ^ (la & 1)) << 4);
    const int D = (la & 30) << 4;
    f32x16 acc = (f32x16)0.0f;
#pragma unroll
    for (int ks = 0; ks < 16; ++ks) {
        bf16x8 af = *(const bf16x8*)(base + C + ((ks << 5) ^ D));
        acc = mfma32(af, wp[ks * 64 + lane], acc);
    }
    if (MODE == 0) {
        if (la == 0) {
            float b = bias[0];
#pragma unroll
            for (int r = 0; r < 16; ++r) {
                int rr = wid * 32 + (r & 3) + 8 * (r >> 2) + 4 * hi;
                float v = acc[r] + b;
                out0[rb + rr] = (v > 0.0f) ? (v + 1.0f) : expf(v);  // elu+1
            }
        }
    } else {
        if (la < 2) {
            float b = bias[la];
            float* dst = (la == 0) ? out0 : out1;
#pragma unroll
            for (int r = 0; r < 16; ++r) {
                int rr = wid * 32 + (r & 3) + 8 * (r >> 2) + 4 * hi;
                dst[rb + rr] = acc[r] + b;
            }
        }
    }
}

// MODE 0: integrand net, rows = s*8192 + i, input [x*(step+1)/2, h(7)], out dz
// MODE 1: h-net, rows = i, input [h(7)], out (offset, log-scale)
template<int MODE>
__global__ __launch_bounds__(256, 4) void mlp_kernel(
    const float* __restrict__ x, const float* __restrict__ h,
    const float* __restrict__ steps,
    const __bf16* __restrict__ w0p, const __bf16* __restrict__ w1p,
    const __bf16* __restrict__ w2p, const __bf16* __restrict__ w3p,
    const float* __restrict__ b0, const float* __restrict__ b1,
    const float* __restrict__ b2, const float* __restrict__ b3,
    float* __restrict__ out0, float* __restrict__ out1) {
    __shared__ __bf16 act[TROWS * 256];   // 32 KB, single in-place buffer

    int tid  = threadIdx.x;
    int lane = tid & 63;
    int wid  = tid >> 6;   // 0..3
    int wc   = wid;
    int rb   = blockIdx.x * TROWS;

    float sc = 0.0f;
    if (MODE == 0) sc = (steps[rb >> 13] + 1.0f) * 0.5f;

    f32x16 acc[2][2];

    // L0: 8(pad16) -> 256, A direct from global (no LDS staging, no barrier)
#pragma unroll
    for (int m = 0; m < 2; ++m)
#pragma unroll
        for (int n = 0; n < 2; ++n) acc[m][n] = (f32x16)0.0f;
    l0_compute<MODE>(x, h, sc, w0p, acc, rb, wc, lane);
    epilogue_store(acc, b0, act, wc, lane);
    __syncthreads();

    // L1: 256 -> 256, in-place: compute, barrier, store, barrier
#pragma unroll
    for (int m = 0; m < 2; ++m)
#pragma unroll
        for (int n = 0; n < 2; ++n) acc[m][n] = (f32x16)0.0f;
    gemm_compute<16>(act, w1p, acc, wc, lane);
    __syncthreads();
    epilogue_store(acc, b1, act, wc, lane);
    __syncthreads();

    // L2: 256 -> 256, in-place
#pragma unroll
    for (int m = 0; m < 2; ++m)
#pragma unroll
        for (int n = 0; n < 2; ++n) acc[m][n] = (f32x16)0.0f;
    gemm_compute<16>(act, w2p, acc, wc, lane);
    __syncthreads();
    epilogue_store(acc, b2, act, wc, lane);
    __syncthreads();

    // final layer: waves 0,1 cover the 64 rows
    if (wid < 2)
        final_layer<MODE>(act, w3p, b3, out0, out1, rb, wid, lane);
}

// ---------------- final reduction ----------------
__global__ void reduce_kernel(const float* __restrict__ dz, const float* __restrict__ x,
                              const float* __restrict__ ho, const float* __restrict__ hs,
                              const float* __restrict__ ccw, float* __restrict__ out) {
    __shared__ float w[S_STEPS];
    int t = threadIdx.x;
    if (t < S_STEPS) w[t] = ccw[t];
    __syncthreads();
    int i = blockIdx.x * blockDim.x + t;
    float acc = 0.0f;
    for (int s = 0; s < S_STEPS; ++s) acc += dz[s * B_SZ + i] * w[s];
    float integral = acc * x[i] * 0.5f;
    out[i] = expf(hs[i]) * integral + ho[i];
}

extern "C" void kernel_launch(void* const* d_in, const int* in_sizes, int n_in,
                              void* d_out, int out_size, void* d_ws, size_t ws_size,
                              hipStream_t stream) {
    (void)in_sizes; (void)n_in; (void)out_size; (void)ws_size;
    const float* x = (const float*)d_in[0];
    const float* h = (const float*)d_in[1];
    const float* iW[4] = {(const float*)d_in[2], (const float*)d_in[4],
                          (const float*)d_in[6], (const float*)d_in[8]};
    const float* ib[4] = {(const float*)d_in[3], (const float*)d_in[5],
                          (const float*)d_in[7], (const float*)d_in[9]};
    const float* hW[4] = {(const float*)d_in[10], (const float*)d_in[12],
                          (const float*)d_in[14], (const float*)d_in[16]};
    const float* hb[4] = {(const float*)d_in[11], (const float*)d_in[13],
                          (const float*)d_in[15], (const float*)d_in[17]};

    size_t off = 0;
    auto alloc = [&](size_t bytes) -> void* {
        void* p = (char*)d_ws + off;
        off += (bytes + 255) & ~(size_t)255;
        return p;
    };
    float*  dz   = (float*)alloc((size_t)M_ROWS * 4);
    float*  ho   = (float*)alloc(B_SZ * 4);
    float*  hs   = (float*)alloc(B_SZ * 4);
    float*  ccw  = (float*)alloc(64 * 4);
    float*  stp  = (float*)alloc(64 * 4);
    __bf16* iW0p = (__bf16*)alloc(8 * 1 * 512 * 2);
    __bf16* iW1p = (__bf16*)alloc(8 * 16 * 512 * 2);
    __bf16* iW2p = (__bf16*)alloc(8 * 16 * 512 * 2);
    __bf16* iW3p = (__bf16*)alloc(1 * 16 * 512 * 2);
    __bf16* hW0p = (__bf16*)alloc(8 * 1 * 512 * 2);
    __bf16* hW1p = (__bf16*)alloc(8 * 16 * 512 * 2);
    __bf16* hW2p = (__bf16*)alloc(8 * 16 * 512 * 2);
    __bf16* hW3p = (__bf16*)alloc(1 * 16 * 512 * 2);

    ccq_kernel<<<1, 64, 0, stream>>>(ccw, stp);

    PackArgs pa;
    const float* srcs[8] = {iW[0], iW[1], iW[2], iW[3], hW[0], hW[1], hW[2], hW[3]};
    __bf16*      dsts[8] = {iW0p, iW1p, iW2p, iW3p, hW0p, hW1p, hW2p, hW3p};
    int Ks[8]  = {8, 256, 256, 256, 7, 256, 256, 256};
    int Ns[8]  = {256, 256, 256, 1, 256, 256, 256, 2};
    int KST[8] = {1, 16, 16, 16, 1, 16, 16, 16};
    int CG[8]  = {8, 8, 8, 1, 8, 8, 8, 1};
    int PM[8]  = {0, 1, 1, 1, 0, 1, 1, 1};   // chi on layers fed by paired epilogue
    int pfx = 0;
    for (int m = 0; m < 8; ++m) {
        pa.src[m] = srcs[m];
        pa.dst[m] = (__hip_bfloat16*)dsts[m];
        pa.Ks[m] = Ks[m]; pa.Ns[m] = Ns[m]; pa.KST[m] = KST[m]; pa.perm[m] = PM[m];
        pa.prefix[m] = pfx;
        pfx += CG[m] * KST[m] * 512;
    }
    pa.prefix[8] = pfx;
    pack_all<<<(pfx + 255) / 256, 256, 0, stream>>>(pa);

    mlp_kernel<0><<<M_ROWS / TROWS, 256, 0, stream>>>(
        x, h, stp, iW0p, iW1p, iW2p, iW3p, ib[0], ib[1], ib[2], ib[3], dz, dz);
    mlp_kernel<1><<<B_SZ / TROWS, 256, 0, stream>>>(
        x, h, stp, hW0p, hW1p, hW2p, hW3p, hb[0], hb[1], hb[2], hb[3], ho, hs);

    reduce_kernel<<<B_SZ / 256, 256, 0, stream>>>(dz, x, ho, hs, ccw, (float*)d_out);
}